// Round 2
// baseline (717.962 us; speedup 1.0000x reference)
//
#include <hip/hip_runtime.h>
#include <hip/hip_bf16.h>
#include <math.h>

#define Bb   16
#define HWn  4096
#define Ff   512
#define Kk   32

typedef __attribute__((ext_vector_type(8))) short  short8;
typedef __attribute__((ext_vector_type(4))) float  f32x4;

// workspace layout (float offsets)
#define WS_ENC   0
#define WS_SSUM  (Bb * Kk * Ff)            // 262144
#define WS_EOUT  (WS_SSUM + 512)           // 262656
#define WS_ATTN  (WS_EOUT + Bb * Ff)       // 270848
#define WS_CWB   (WS_ATTN + Bb * Ff)       // 279040 (16384 bf16 = 8192 float slots)
#define WS_C2    (WS_CWB + 8192)           // 287232
#define WS_SM    (WS_C2 + 32)              // 287264

// ---------------------------------------------------------------------------
// prep: zero enc_acc+s_sum; convert cw->bf16; fold c2[k]*sm[k]*log2e, sm[k]*log2e
// ---------------------------------------------------------------------------
__global__ void prep(const float* __restrict__ cw, const float* __restrict__ smth,
                     float* __restrict__ zero_region, unsigned short* __restrict__ cwb,
                     float* __restrict__ c2l2, float* __restrict__ sml2)
{
    const int t = threadIdx.x;
    if (blockIdx.x == 0) {
        const float4* c4 = (const float4*)cw;
        #pragma unroll
        for (int j = 0; j < 16; ++j) {
            const int i = t + j * 256;             // 4096 float4 total
            const float4 v = c4[i];
            union { __hip_bfloat162 h; unsigned int u; } p0, p1;
            p0.h = __float22bfloat162_rn(make_float2(v.x, v.y));
            p1.h = __float22bfloat162_rn(make_float2(v.z, v.w));
            *reinterpret_cast<uint2*>(&cwb[i * 4]) = make_uint2(p0.u, p1.u);
        }
        const int k = t >> 3, sk = t & 7;
        float p = 0.f;
        #pragma unroll
        for (int j = 0; j < 16; ++j) {
            const float4 v = c4[k * 128 + sk + j * 8];
            p = fmaf(v.x, v.x, fmaf(v.y, v.y, fmaf(v.z, v.z, fmaf(v.w, v.w, p))));
        }
        p += __shfl_xor(p, 1); p += __shfl_xor(p, 2); p += __shfl_xor(p, 4);
        if (sk == 0) {
            const float L2E = 1.4426950408889634f;
            const float sm = smth[k];
            sml2[k] = sm * L2E;
            c2l2[k] = p * sm * L2E;
        }
    } else {
        float4* z = (float4*)zero_region;          // 262656 floats = 65664 float4
        for (int i = (blockIdx.x - 1) * 256 + t; i < 65664; i += 127 * 256)
            z[i] = make_float4(0.f, 0.f, 0.f, 0.f);
    }
}

// ---------------------------------------------------------------------------
// enc_pass v2: grid (64, 16), block 256 (4 waves). Each block: 64 rows (2 tiles
// of 32). Phase 1 = bf16 MFMA xc^T + in-register softmax (waves 0,1).
// Phase 2 = VALU rank-32 accumulate, wave w owns k in [8w,8w+8), lane owns 8 f.
// ---------------------------------------------------------------------------
__global__ __launch_bounds__(256, 3) void enc_pass(
    const float* __restrict__ x, const unsigned short* __restrict__ cwb,
    const float* __restrict__ c2l2, const float* __restrict__ sml2,
    float* __restrict__ enc_acc, float* __restrict__ s_sum)
{
    __shared__ __align__(16) unsigned short fb16[32 * 512];  // 32 KB, chunk-XOR swizzled
    __shared__ float sN[32][36];                             // s[n][k], padded
    __shared__ float x2s[32];
    __shared__ float sm_s[32], c2_s[32];

    const int tid  = threadIdx.x;
    const int wave = tid >> 6, lane = tid & 63;
    const int b    = blockIdx.y;
    const int row0 = blockIdx.x * 64;

    if (tid < 32) { sm_s[tid] = sml2[tid]; c2_s[tid] = c2l2[tid]; }

    float acc[8][8];
    #pragma unroll
    for (int j = 0; j < 8; ++j)
        #pragma unroll
        for (int i = 0; i < 8; ++i) acc[j][i] = 0.f;
    float ssl[8] = {0.f, 0.f, 0.f, 0.f, 0.f, 0.f, 0.f, 0.f};

    for (int t = 0; t < 2; ++t) {
        if (t) __syncthreads();                    // guard fb16/sN reuse
        const float4* xr4 = (const float4*)(x + ((size_t)b * HWn + row0 + t * 32) * Ff);
        // ---- stage fp32 -> bf16 (swizzled) + fp32 x2 ----
        {
            const int n = tid >> 3, f8 = tid & 7;  // 8 threads per row
            float p = 0.f;
            #pragma unroll
            for (int j = 0; j < 16; ++j) {
                const int f4 = f8 + j * 8;
                const float4 v = xr4[n * 128 + f4];
                p = fmaf(v.x, v.x, fmaf(v.y, v.y, fmaf(v.z, v.z, fmaf(v.w, v.w, p))));
                union { __hip_bfloat162 h; unsigned int u; } p0, p1;
                p0.h = __float22bfloat162_rn(make_float2(v.x, v.y));
                p1.h = __float22bfloat162_rn(make_float2(v.z, v.w));
                const int chunk = f4 >> 1;
                const int idx = n * 512 + (((chunk ^ (n & 7)) << 3) | ((f4 & 1) << 2));
                *reinterpret_cast<uint2*>(&fb16[idx]) = make_uint2(p0.u, p1.u);
            }
            p += __shfl_xor(p, 1); p += __shfl_xor(p, 2); p += __shfl_xor(p, 4);
            if (f8 == 0) x2s[n] = p;
        }
        __syncthreads();
        // ---- phase 1: MFMA xc^T + softmax (waves 0,1; 2,3 idle to barrier) ----
        if (wave < 2) {
            const int col = lane & 15, g = lane >> 4;
            const int nl  = wave * 16 + col;
            f32x4 c0 = {0.f, 0.f, 0.f, 0.f}, c1 = {0.f, 0.f, 0.f, 0.f};
            const unsigned short* arow0 = cwb + col * 512 + g * 8;
            const unsigned short* arow1 = arow0 + 16 * 512;
            const int nswz = (nl & 7) << 3;
            #pragma unroll
            for (int fs = 0; fs < 16; ++fs) {
                const short8 a0 = *(const short8*)(arow0 + fs * 32);
                const short8 a1 = *(const short8*)(arow1 + fs * 32);
                const short8 bf = *(const short8*)&fb16[nl * 512 + ((((fs * 4 + g) << 3)) ^ nswz)];
                c0 = __builtin_amdgcn_mfma_f32_16x16x32_bf16(a0, bf, c0, 0, 0, 0);
                c1 = __builtin_amdgcn_mfma_f32_16x16x32_bf16(a1, bf, c1, 0, 0, 0);
            }
            const float x2v = x2s[nl];
            float lg[8];
            #pragma unroll
            for (int r = 0; r < 4; ++r) {
                const int k0 = g * 4 + r;
                lg[r]     = fmaf(sm_s[k0],      fmaf(-2.f, c0[r], x2v), c2_s[k0]);
                lg[4 + r] = fmaf(sm_s[k0 + 16], fmaf(-2.f, c1[r], x2v), c2_s[k0 + 16]);
            }
            float m = lg[0];
            #pragma unroll
            for (int j = 1; j < 8; ++j) m = fmaxf(m, lg[j]);
            m = fmaxf(m, __shfl_xor(m, 16)); m = fmaxf(m, __shfl_xor(m, 32));
            float e[8], sum = 0.f;
            #pragma unroll
            for (int j = 0; j < 8; ++j) { e[j] = exp2f(lg[j] - m); sum += e[j]; }
            sum += __shfl_xor(sum, 16); sum += __shfl_xor(sum, 32);
            const float inv = 1.f / sum;
            #pragma unroll
            for (int r = 0; r < 4; ++r) {
                const float s0 = e[r] * inv, s1 = e[4 + r] * inv;
                sN[nl][g * 4 + r]      = s0;
                sN[nl][16 + g * 4 + r] = s1;
                ssl[r] += s0; ssl[4 + r] += s1;
            }
        }
        __syncthreads();
        // ---- phase 2: acc[k][f] += s[n][k] * feats[n][f] over 32 rows ----
        {
            const int kw = wave * 8;
            #pragma unroll 2
            for (int n = 0; n < 32; ++n) {
                const f32x4 s0 = *(const f32x4*)&sN[n][kw];
                const f32x4 s1 = *(const f32x4*)&sN[n][kw + 4];
                const uint4 u = *(const uint4*)&fb16[n * 512 + (((lane ^ (n & 7))) << 3)];
                float fx[8];
                fx[0] = __uint_as_float(u.x << 16);
                fx[1] = __uint_as_float(u.x & 0xffff0000u);
                fx[2] = __uint_as_float(u.y << 16);
                fx[3] = __uint_as_float(u.y & 0xffff0000u);
                fx[4] = __uint_as_float(u.z << 16);
                fx[5] = __uint_as_float(u.z & 0xffff0000u);
                fx[6] = __uint_as_float(u.w << 16);
                fx[7] = __uint_as_float(u.w & 0xffff0000u);
                #pragma unroll
                for (int j = 0; j < 4; ++j) {
                    const float sj0 = s0[j], sj1 = s1[j];
                    #pragma unroll
                    for (int i = 0; i < 8; ++i) {
                        acc[j][i]     = fmaf(sj0, fx[i], acc[j][i]);
                        acc[4 + j][i] = fmaf(sj1, fx[i], acc[4 + j][i]);
                    }
                }
            }
        }
    }
    // ---- s_sum writeback (waves 0,1) ----
    if (wave < 2) {
        const int g = lane >> 4;
        #pragma unroll
        for (int j = 0; j < 8; ++j) {
            float v = ssl[j];
            v += __shfl_xor(v, 1); v += __shfl_xor(v, 2);
            v += __shfl_xor(v, 4); v += __shfl_xor(v, 8);
            if ((lane & 15) == 0) {
                const int k = ((j & 4) << 2) + g * 4 + (j & 3);
                atomicAdd(&s_sum[b * Kk + k], v);
            }
        }
    }
    // ---- enc_acc writeback (atomic, 64 per thread) ----
    {
        float* basep = enc_acc + (((size_t)b * Kk + wave * 8) * Ff) + lane * 8;
        #pragma unroll
        for (int j = 0; j < 8; ++j)
            #pragma unroll
            for (int i = 0; i < 8; ++i)
                atomicAdd(basep + j * Ff + i, acc[j][i]);
    }
}

// ---------------------------------------------------------------------------
// enc_finish: enc = enc_acc - s_sum*cw; BN + ReLU; sum over k; se_loss.
// ---------------------------------------------------------------------------
__global__ void enc_finish(const float* __restrict__ enc_acc,
                           const float* __restrict__ s_sum,
                           const float* __restrict__ cw,
                           const float* __restrict__ gamma,
                           const float* __restrict__ beta,
                           const float* __restrict__ mean,
                           const float* __restrict__ var,
                           const float* __restrict__ se_w,
                           const float* __restrict__ se_b,
                           float* __restrict__ enc_out,
                           float* __restrict__ se_out)
{
    __shared__ float ss[Kk];
    __shared__ float red[8];
    const int b = blockIdx.x, f = threadIdx.x;
    if (f < Kk) ss[f] = s_sum[b * Kk + f];
    __syncthreads();
    const float m  = mean[f];
    const float g  = gamma[f];
    const float bt = beta[f];
    const float iv = rsqrtf(var[f] + 1e-3f);
    float a = 0.f;
    #pragma unroll 4
    for (int k = 0; k < Kk; ++k) {
        float v = enc_acc[((long)b * Kk + k) * Ff + f] - ss[k] * cw[k * Ff + f];
        v = (v - m) * iv * g + bt;
        a += fmaxf(v, 0.f);
    }
    enc_out[b * Ff + f] = a;
    float p = a * se_w[f];
    p += __shfl_down(p, 32); p += __shfl_down(p, 16); p += __shfl_down(p, 8);
    p += __shfl_down(p, 4);  p += __shfl_down(p, 2);  p += __shfl_down(p, 1);
    if ((f & 63) == 0) red[f >> 6] = p;
    __syncthreads();
    if (f == 0) {
        float t = 0.f;
        #pragma unroll
        for (int i = 0; i < 8; ++i) t += red[i];
        se_out[b] = t + se_b[0];
    }
}

// ---------------------------------------------------------------------------
// attn_fc: attn[b][f] = sigmoid(enc_out[b] . W[:,f] + bias[f])
// ---------------------------------------------------------------------------
__global__ void attn_fc(const float* __restrict__ enc_out,
                        const float* __restrict__ W,
                        const float* __restrict__ bias,
                        float* __restrict__ attn)
{
    __shared__ float eo[Ff];
    const int b = blockIdx.x, f = threadIdx.x;
    eo[f] = enc_out[b * Ff + f];
    __syncthreads();
    float a = bias[f];
    #pragma unroll 8
    for (int fp = 0; fp < Ff; ++fp) a = fmaf(eo[fp], W[fp * Ff + f], a);
    attn[b * Ff + f] = 1.f / (1.f + expf(-a));
}

// ---------------------------------------------------------------------------
// bcast_mul: featuremaps = attn (broadcast over H,W) * inputs
// ---------------------------------------------------------------------------
__global__ void bcast_mul(const float4* __restrict__ x4,
                          const float* __restrict__ attn,
                          float4* __restrict__ o4)
{
    const int stride = gridDim.x * blockDim.x;
    const int total4 = Bb * HWn * Ff / 4;   // 8388608
    for (int i = blockIdx.x * blockDim.x + threadIdx.x; i < total4; i += stride) {
        const float4 v = x4[i];
        const int f4 = i & 127;
        const int bb = i >> 19;             // HWn*Ff/4 = 2^19
        const float4 a = *reinterpret_cast<const float4*>(&attn[bb * Ff + f4 * 4]);
        o4[i] = make_float4(v.x * a.x, v.y * a.y, v.z * a.z, v.w * a.w);
    }
}

extern "C" void kernel_launch(void* const* d_in, const int* in_sizes, int n_in,
                              void* d_out, int out_size, void* d_ws, size_t ws_size,
                              hipStream_t stream)
{
    (void)in_sizes; (void)n_in; (void)out_size; (void)ws_size;
    const float* x     = (const float*)d_in[0];
    const float* cw    = (const float*)d_in[1];
    const float* smth  = (const float*)d_in[2];
    const float* gamma = (const float*)d_in[3];
    const float* beta  = (const float*)d_in[4];
    const float* mean  = (const float*)d_in[5];
    const float* var   = (const float*)d_in[6];
    const float* Wenc  = (const float*)d_in[7];
    const float* benc  = (const float*)d_in[8];
    const float* Wse   = (const float*)d_in[9];
    const float* bse   = (const float*)d_in[10];

    float* out = (float*)d_out;
    float* ws  = (float*)d_ws;
    float* enc_acc = ws + WS_ENC;
    float* ssum    = ws + WS_SSUM;
    float* eout    = ws + WS_EOUT;
    float* attn    = ws + WS_ATTN;
    unsigned short* cwb = (unsigned short*)(ws + WS_CWB);
    float* c2l2    = ws + WS_C2;
    float* sml2    = ws + WS_SM;

    prep<<<128, 256, 0, stream>>>(cw, smth, ws, cwb, c2l2, sml2);
    enc_pass<<<dim3(64, Bb), 256, 0, stream>>>(x, cwb, c2l2, sml2, enc_acc, ssum);
    enc_finish<<<Bb, 512, 0, stream>>>(enc_acc, ssum, cw, gamma, beta, mean, var,
                                       Wse, bse, eout, out + (long)Bb * HWn * Ff);
    attn_fc<<<Bb, 512, 0, stream>>>(eout, Wenc, benc, attn);
    bcast_mul<<<2048, 256, 0, stream>>>((const float4*)x, attn, (float4*)out);
}

// Round 3
// 172.206 us; speedup vs baseline: 4.1692x; 4.1692x over previous
//
#include <hip/hip_runtime.h>
#include <hip/hip_bf16.h>
#include <math.h>

#define Bb   16
#define HWn  4096
#define Ff   512
#define Kk   32

typedef __attribute__((ext_vector_type(8))) short  short8;
typedef __attribute__((ext_vector_type(4))) float  f32x4;

// ws layout (float offsets) — small stuff only
#define WS_SSUM  0                          // 512
#define WS_EOUT  512                        // 8192
#define WS_ATTN  (WS_EOUT + Bb * Ff)        // 8192
#define WS_CWB   (WS_ATTN + Bb * Ff)        // 8192 float slots (16384 bf16)
#define WS_C2    (WS_CWB + 8192)            // 32
#define WS_SM    (WS_C2 + 32)               // 32

// d_out scratch layout (float offsets into the 33.5M featuremap region):
//   partials: 0 .. 16*32*32*512 = 8,388,608
//   enc_red : 16,777,216 .. +262,144
#define SCR_PART 0
#define SCR_RED  16777216

// ---------------------------------------------------------------------------
// prep: cw -> bf16; fold c2[k]*sm[k]*log2e and sm[k]*log2e. 1 block, 256 thr.
// ---------------------------------------------------------------------------
__global__ void prep(const float* __restrict__ cw, const float* __restrict__ smth,
                     unsigned short* __restrict__ cwb,
                     float* __restrict__ c2l2, float* __restrict__ sml2)
{
    const int t = threadIdx.x;
    const float4* c4 = (const float4*)cw;
    #pragma unroll
    for (int j = 0; j < 16; ++j) {
        const int i = t + j * 256;             // 4096 float4 total
        const float4 v = c4[i];
        union { __hip_bfloat162 h; unsigned int u; } p0, p1;
        p0.h = __float22bfloat162_rn(make_float2(v.x, v.y));
        p1.h = __float22bfloat162_rn(make_float2(v.z, v.w));
        *reinterpret_cast<uint2*>(&cwb[i * 4]) = make_uint2(p0.u, p1.u);
    }
    const int k = t >> 3, sk = t & 7;
    float p = 0.f;
    #pragma unroll
    for (int j = 0; j < 16; ++j) {
        const float4 v = c4[k * 128 + sk + j * 8];
        p = fmaf(v.x, v.x, fmaf(v.y, v.y, fmaf(v.z, v.z, fmaf(v.w, v.w, p))));
    }
    p += __shfl_xor(p, 1); p += __shfl_xor(p, 2); p += __shfl_xor(p, 4);
    if (sk == 0) {
        const float L2E = 1.4426950408889634f;
        const float sm = smth[k];
        sml2[k] = sm * L2E;
        c2l2[k] = p * sm * L2E;
    }
}

// ---------------------------------------------------------------------------
// enc_pass v3: grid (32, 16), block 256. Each block: 128 rows (4 tiles of 32).
// Phase 1 = bf16 MFMA xc^T + in-register softmax (waves 0,1).
// Phase 2 = fp32 VALU rank-32 accumulate, wave w owns k [8w,8w+8), lane 8 f.
// Writeback: ONE 32x512 fp32 partial per block into d_out scratch (no atomics).
// ---------------------------------------------------------------------------
__global__ __launch_bounds__(256, 2) void enc_pass(
    const float* __restrict__ x, const unsigned short* __restrict__ cwb,
    const float* __restrict__ c2l2, const float* __restrict__ sml2,
    float* __restrict__ part, float* __restrict__ s_sum)
{
    __shared__ __align__(16) unsigned short fb16[32 * 512];  // 32 KB, chunk-XOR swizzled
    __shared__ float sN[32][36];
    __shared__ float x2s[32];
    __shared__ float sm_s[32], c2_s[32];

    const int tid  = threadIdx.x;
    const int wave = tid >> 6, lane = tid & 63;
    const int b    = blockIdx.y;
    const int cx   = blockIdx.x;
    const int row0 = cx * 128;

    if (tid < 32) { sm_s[tid] = sml2[tid]; c2_s[tid] = c2l2[tid]; }

    float acc[8][8];
    #pragma unroll
    for (int j = 0; j < 8; ++j)
        #pragma unroll
        for (int i = 0; i < 8; ++i) acc[j][i] = 0.f;
    float ssl[8] = {0.f, 0.f, 0.f, 0.f, 0.f, 0.f, 0.f, 0.f};

    for (int t = 0; t < 4; ++t) {
        if (t) __syncthreads();                    // guard fb16/sN reuse
        const float4* xr4 = (const float4*)(x + ((size_t)b * HWn + row0 + t * 32) * Ff);
        // ---- stage fp32 -> bf16 (swizzled) + fp32 x2 ----
        {
            const int n = tid >> 3, f8 = tid & 7;  // 8 threads per row
            float p = 0.f;
            #pragma unroll
            for (int j = 0; j < 16; ++j) {
                const int f4 = f8 + j * 8;
                const float4 v = xr4[n * 128 + f4];
                p = fmaf(v.x, v.x, fmaf(v.y, v.y, fmaf(v.z, v.z, fmaf(v.w, v.w, p))));
                union { __hip_bfloat162 h; unsigned int u; } p0, p1;
                p0.h = __float22bfloat162_rn(make_float2(v.x, v.y));
                p1.h = __float22bfloat162_rn(make_float2(v.z, v.w));
                const int chunk = f4 >> 1;
                const int idx = n * 512 + (((chunk ^ (n & 7)) << 3) | ((f4 & 1) << 2));
                *reinterpret_cast<uint2*>(&fb16[idx]) = make_uint2(p0.u, p1.u);
            }
            p += __shfl_xor(p, 1); p += __shfl_xor(p, 2); p += __shfl_xor(p, 4);
            if (f8 == 0) x2s[n] = p;
        }
        __syncthreads();
        // ---- phase 1: MFMA xc^T + softmax (waves 0,1) ----
        if (wave < 2) {
            const int col = lane & 15, g = lane >> 4;
            const int nl  = wave * 16 + col;
            f32x4 c0 = {0.f, 0.f, 0.f, 0.f}, c1 = {0.f, 0.f, 0.f, 0.f};
            const unsigned short* arow0 = cwb + col * 512 + g * 8;
            const unsigned short* arow1 = arow0 + 16 * 512;
            const int nswz = (nl & 7) << 3;
            #pragma unroll
            for (int fs = 0; fs < 16; ++fs) {
                const short8 a0 = *(const short8*)(arow0 + fs * 32);
                const short8 a1 = *(const short8*)(arow1 + fs * 32);
                const short8 bf = *(const short8*)&fb16[nl * 512 + ((((fs * 4 + g) << 3)) ^ nswz)];
                c0 = __builtin_amdgcn_mfma_f32_16x16x32_bf16(a0, bf, c0, 0, 0, 0);
                c1 = __builtin_amdgcn_mfma_f32_16x16x32_bf16(a1, bf, c1, 0, 0, 0);
            }
            const float x2v = x2s[nl];
            float lg[8];
            #pragma unroll
            for (int r = 0; r < 4; ++r) {
                const int k0 = g * 4 + r;
                lg[r]     = fmaf(sm_s[k0],      fmaf(-2.f, c0[r], x2v), c2_s[k0]);
                lg[4 + r] = fmaf(sm_s[k0 + 16], fmaf(-2.f, c1[r], x2v), c2_s[k0 + 16]);
            }
            float m = lg[0];
            #pragma unroll
            for (int j = 1; j < 8; ++j) m = fmaxf(m, lg[j]);
            m = fmaxf(m, __shfl_xor(m, 16)); m = fmaxf(m, __shfl_xor(m, 32));
            float e[8], sum = 0.f;
            #pragma unroll
            for (int j = 0; j < 8; ++j) { e[j] = exp2f(lg[j] - m); sum += e[j]; }
            sum += __shfl_xor(sum, 16); sum += __shfl_xor(sum, 32);
            const float inv = 1.f / sum;
            #pragma unroll
            for (int r = 0; r < 4; ++r) {
                const float s0 = e[r] * inv, s1 = e[4 + r] * inv;
                sN[nl][g * 4 + r]      = s0;
                sN[nl][16 + g * 4 + r] = s1;
                ssl[r] += s0; ssl[4 + r] += s1;
            }
        }
        __syncthreads();
        // ---- phase 2: acc[k][f] += s[n][k] * feats[n][f] over 32 rows ----
        {
            const int kw = wave * 8;
            #pragma unroll 2
            for (int n = 0; n < 32; ++n) {
                const f32x4 s0 = *(const f32x4*)&sN[n][kw];
                const f32x4 s1 = *(const f32x4*)&sN[n][kw + 4];
                const uint4 u = *(const uint4*)&fb16[n * 512 + (((lane ^ (n & 7))) << 3)];
                float fx[8];
                fx[0] = __uint_as_float(u.x << 16);
                fx[1] = __uint_as_float(u.x & 0xffff0000u);
                fx[2] = __uint_as_float(u.y << 16);
                fx[3] = __uint_as_float(u.y & 0xffff0000u);
                fx[4] = __uint_as_float(u.z << 16);
                fx[5] = __uint_as_float(u.z & 0xffff0000u);
                fx[6] = __uint_as_float(u.w << 16);
                fx[7] = __uint_as_float(u.w & 0xffff0000u);
                #pragma unroll
                for (int j = 0; j < 4; ++j) {
                    const float sj0 = s0[j], sj1 = s1[j];
                    #pragma unroll
                    for (int i = 0; i < 8; ++i) {
                        acc[j][i]     = fmaf(sj0, fx[i], acc[j][i]);
                        acc[4 + j][i] = fmaf(sj1, fx[i], acc[4 + j][i]);
                    }
                }
            }
        }
    }
    // ---- s_sum writeback (waves 0,1; tiny atomic volume) ----
    if (wave < 2) {
        const int g = lane >> 4;
        #pragma unroll
        for (int j = 0; j < 8; ++j) {
            float v = ssl[j];
            v += __shfl_xor(v, 1); v += __shfl_xor(v, 2);
            v += __shfl_xor(v, 4); v += __shfl_xor(v, 8);
            if ((lane & 15) == 0) {
                const int k = ((j & 4) << 2) + g * 4 + (j & 3);
                atomicAdd(&s_sum[b * Kk + k], v);
            }
        }
    }
    // ---- partial writeback: plain coalesced float4 stores ----
    {
        float* basep = part + (((size_t)(b * 32 + cx) * Kk) + wave * 8) * Ff + lane * 8;
        #pragma unroll
        for (int j = 0; j < 8; ++j) {
            *reinterpret_cast<float4*>(basep + j * Ff) =
                make_float4(acc[j][0], acc[j][1], acc[j][2], acc[j][3]);
            *reinterpret_cast<float4*>(basep + j * Ff + 4) =
                make_float4(acc[j][4], acc[j][5], acc[j][6], acc[j][7]);
        }
    }
}

// ---------------------------------------------------------------------------
// enc_red: sum the 32 per-chunk partials -> enc[b][k][f]. grid 1024 x 256.
// ---------------------------------------------------------------------------
__global__ void enc_red(const float* __restrict__ scr, float* __restrict__ outp)
{
    const int idx = blockIdx.x * 256 + threadIdx.x;    // 0 .. 262143
    const int b   = idx >> 14;
    const int rem = idx & 16383;                       // k*512 + f
    const float* p = scr + (size_t)b * 32 * 16384 + rem;
    float a = 0.f;
    #pragma unroll
    for (int c = 0; c < 32; ++c) a += p[c * 16384];
    outp[idx] = a;
}

// ---------------------------------------------------------------------------
// enc_finish: enc = enc_red - s_sum*cw; BN + ReLU; sum over k; se_loss.
// ---------------------------------------------------------------------------
__global__ void enc_finish(const float* __restrict__ enc_acc,
                           const float* __restrict__ s_sum,
                           const float* __restrict__ cw,
                           const float* __restrict__ gamma,
                           const float* __restrict__ beta,
                           const float* __restrict__ mean,
                           const float* __restrict__ var,
                           const float* __restrict__ se_w,
                           const float* __restrict__ se_b,
                           float* __restrict__ enc_out,
                           float* __restrict__ se_out)
{
    __shared__ float ss[Kk];
    __shared__ float red[8];
    const int b = blockIdx.x, f = threadIdx.x;
    if (f < Kk) ss[f] = s_sum[b * Kk + f];
    __syncthreads();
    const float m  = mean[f];
    const float g  = gamma[f];
    const float bt = beta[f];
    const float iv = rsqrtf(var[f] + 1e-3f);
    float a = 0.f;
    #pragma unroll 4
    for (int k = 0; k < Kk; ++k) {
        float v = enc_acc[((long)b * Kk + k) * Ff + f] - ss[k] * cw[k * Ff + f];
        v = (v - m) * iv * g + bt;
        a += fmaxf(v, 0.f);
    }
    enc_out[b * Ff + f] = a;
    float p = a * se_w[f];
    p += __shfl_down(p, 32); p += __shfl_down(p, 16); p += __shfl_down(p, 8);
    p += __shfl_down(p, 4);  p += __shfl_down(p, 2);  p += __shfl_down(p, 1);
    if ((f & 63) == 0) red[f >> 6] = p;
    __syncthreads();
    if (f == 0) {
        float t = 0.f;
        #pragma unroll
        for (int i = 0; i < 8; ++i) t += red[i];
        se_out[b] = t + se_b[0];
    }
}

// ---------------------------------------------------------------------------
// attn_fc: grid 8 blocks x 512. Block fg computes f in [fg*64, fg*64+64) for
// all 16 b; W column-block read exactly once (1 MB total W traffic).
// ---------------------------------------------------------------------------
__global__ void attn_fc(const float* __restrict__ enc_out,
                        const float* __restrict__ W,
                        const float* __restrict__ bias,
                        float* __restrict__ attn)
{
    __shared__ float eo[Bb][Ff];                       // 32 KB
    const int t = threadIdx.x, fg = blockIdx.x;
    #pragma unroll
    for (int j = 0; j < 4; ++j)
        reinterpret_cast<float4*>(&eo[0][0])[t + j * 512] =
            reinterpret_cast<const float4*>(enc_out)[t + j * 512];
    __syncthreads();
    const int f  = fg * 64 + (t & 63);
    const int b0 = t >> 6;                             // == wave id, 0..7
    float a0 = bias[f], a1 = bias[f];
    #pragma unroll 8
    for (int fp = 0; fp < Ff; ++fp) {
        const float w = W[fp * Ff + f];
        a0 = fmaf(eo[b0][fp],     w, a0);
        a1 = fmaf(eo[b0 + 8][fp], w, a1);
    }
    attn[b0 * Ff + f]       = 1.f / (1.f + expf(-a0));
    attn[(b0 + 8) * Ff + f] = 1.f / (1.f + expf(-a1));
}

// ---------------------------------------------------------------------------
// bcast_mul: featuremaps = attn (broadcast over H,W) * inputs
// ---------------------------------------------------------------------------
__global__ void bcast_mul(const float4* __restrict__ x4,
                          const float* __restrict__ attn,
                          float4* __restrict__ o4)
{
    const int stride = gridDim.x * blockDim.x;
    const int total4 = Bb * HWn * Ff / 4;   // 8388608
    for (int i = blockIdx.x * blockDim.x + threadIdx.x; i < total4; i += stride) {
        const float4 v = x4[i];
        const int f4 = i & 127;
        const int bb = i >> 19;             // HWn*Ff/4 = 2^19
        const float4 a = *reinterpret_cast<const float4*>(&attn[bb * Ff + f4 * 4]);
        o4[i] = make_float4(v.x * a.x, v.y * a.y, v.z * a.z, v.w * a.w);
    }
}

extern "C" void kernel_launch(void* const* d_in, const int* in_sizes, int n_in,
                              void* d_out, int out_size, void* d_ws, size_t ws_size,
                              hipStream_t stream)
{
    (void)in_sizes; (void)n_in; (void)out_size; (void)ws_size;
    const float* x     = (const float*)d_in[0];
    const float* cw    = (const float*)d_in[1];
    const float* smth  = (const float*)d_in[2];
    const float* gamma = (const float*)d_in[3];
    const float* beta  = (const float*)d_in[4];
    const float* mean  = (const float*)d_in[5];
    const float* var   = (const float*)d_in[6];
    const float* Wenc  = (const float*)d_in[7];
    const float* benc  = (const float*)d_in[8];
    const float* Wse   = (const float*)d_in[9];
    const float* bse   = (const float*)d_in[10];

    float* out = (float*)d_out;
    float* ws  = (float*)d_ws;
    float* ssum = ws + WS_SSUM;
    float* eout = ws + WS_EOUT;
    float* attn = ws + WS_ATTN;
    unsigned short* cwb = (unsigned short*)(ws + WS_CWB);
    float* c2l2 = ws + WS_C2;
    float* sml2 = ws + WS_SM;

    float* scr_part = out + SCR_PART;    // d_out featuremap region as scratch
    float* scr_red  = out + SCR_RED;

    hipMemsetAsync(ssum, 0, (size_t)Bb * Kk * sizeof(float), stream);
    prep<<<1, 256, 0, stream>>>(cw, smth, cwb, c2l2, sml2);
    enc_pass<<<dim3(32, Bb), 256, 0, stream>>>(x, cwb, c2l2, sml2, scr_part, ssum);
    enc_red<<<1024, 256, 0, stream>>>(scr_part, scr_red);
    enc_finish<<<Bb, 512, 0, stream>>>(scr_red, ssum, cw, gamma, beta, mean, var,
                                       Wse, bse, eout, out + (long)Bb * HWn * Ff);
    attn_fc<<<8, 512, 0, stream>>>(eout, Wenc, benc, attn);
    bcast_mul<<<2048, 256, 0, stream>>>((const float4*)x, attn, (float4*)out);
}

// Round 4
// 157.562 us; speedup vs baseline: 4.5567x; 1.0929x over previous
//
#include <hip/hip_runtime.h>
#include <hip/hip_bf16.h>
#include <math.h>

#define Bb   16
#define HWn  4096
#define Ff   512
#define Kk   32

typedef __attribute__((ext_vector_type(8))) short  short8;
typedef __attribute__((ext_vector_type(4))) float  f32x4;

// ws layout (float offsets) — small stuff only
#define WS_SSUM  0                          // 512
#define WS_EOUT  512
#define WS_ATTN  (WS_EOUT + Bb * Ff)
#define WS_CWB   (WS_ATTN + Bb * Ff)        // 8192 float slots (16384 bf16)
#define WS_C2    (WS_CWB + 8192)
#define WS_SM    (WS_C2 + 32)

// d_out scratch layout (float offsets into the 33.5M featuremap region)
#define SCR_PART 0
#define SCR_RED  16777216

static __device__ __forceinline__ unsigned int pack2bf(float a, float b) {
    union { __hip_bfloat162 h; unsigned int u; } p;
    p.h = __float22bfloat162_rn(make_float2(a, b));
    return p.u;
}
static __device__ __forceinline__ unsigned short f2bf(float v) {
    union { __hip_bfloat16 h; unsigned short u; } c;
    c.h = __float2bfloat16(v);
    return c.u;
}

// ---------------------------------------------------------------------------
// prep: cw -> bf16; fold c2[k]*sm[k]*log2e and sm[k]*log2e. 1 block, 256 thr.
// ---------------------------------------------------------------------------
__global__ void prep(const float* __restrict__ cw, const float* __restrict__ smth,
                     unsigned short* __restrict__ cwb,
                     float* __restrict__ c2l2, float* __restrict__ sml2)
{
    const int t = threadIdx.x;
    const float4* c4 = (const float4*)cw;
    #pragma unroll
    for (int j = 0; j < 16; ++j) {
        const int i = t + j * 256;             // 4096 float4 total
        const float4 v = c4[i];
        *reinterpret_cast<uint2*>(&cwb[i * 4]) =
            make_uint2(pack2bf(v.x, v.y), pack2bf(v.z, v.w));
    }
    const int k = t >> 3, sk = t & 7;
    float p = 0.f;
    #pragma unroll
    for (int j = 0; j < 16; ++j) {
        const float4 v = c4[k * 128 + sk + j * 8];
        p = fmaf(v.x, v.x, fmaf(v.y, v.y, fmaf(v.z, v.z, fmaf(v.w, v.w, p))));
    }
    p += __shfl_xor(p, 1); p += __shfl_xor(p, 2); p += __shfl_xor(p, 4);
    if (sk == 0) {
        const float L2E = 1.4426950408889634f;
        const float sm = smth[k];
        sml2[k] = sm * L2E;
        c2l2[k] = p * sm * L2E;
    }
}

// ---------------------------------------------------------------------------
// enc_pass v4: grid (32, 16), block 256. 128 rows/block (4 tiles of 32).
//  stage (reg-pipelined): fp32 loads -> bf16 row-major fb16 + transposed xT
//  phase 1 (waves 0,1): MFMA xc^T + in-register softmax -> bf16 sT, ssl
//  phase 2 (all 4 waves): MFMA enc[k][f] += sT[k][n] * x[n][f]
//  writeback: one 32x512 fp32 partial per block, plain stores.
// ---------------------------------------------------------------------------
__global__ __launch_bounds__(256, 2) void enc_pass(
    const float* __restrict__ x, const unsigned short* __restrict__ cwb,
    const float* __restrict__ c2l2, const float* __restrict__ sml2,
    float* __restrict__ part, float* __restrict__ s_sum)
{
    __shared__ __align__(16) unsigned short fb16[32 * 512];  // 32 KB row-major (swizzled)
    __shared__ __align__(16) unsigned short xTl[512 * 36];   // 36 KB transposed [f][n], pad 36
    __shared__ __align__(16) unsigned short sTl[32 * 32];    // 2 KB s^T bf16 [k][n]
    __shared__ float x2s[32];
    __shared__ float sm_s[32], c2_s[32];

    const int tid  = threadIdx.x;
    const int wave = tid >> 6, lane = tid & 63;
    const int col  = lane & 15, g = lane >> 4;
    const int b    = blockIdx.y;
    const int cx   = blockIdx.x;
    const int row0 = cx * 128;

    if (tid < 32) { sm_s[tid] = sml2[tid]; c2_s[tid] = c2l2[tid]; }

    // staging mapping: thread owns row-pair 2*n2, 2*n2+1; f-column f16
    const int n2  = tid >> 4;        // 0..15
    const int f16 = tid & 15;        // float4 column within 16-group

    f32x4 accm[16];
    #pragma unroll
    for (int i = 0; i < 16; ++i) accm[i] = (f32x4){0.f, 0.f, 0.f, 0.f};
    float ssl[8] = {0.f, 0.f, 0.f, 0.f, 0.f, 0.f, 0.f, 0.f};

    const float4* xb4 = (const float4*)(x + ((size_t)b * HWn + row0) * Ff);
    float4 r0[8], r1[8];
    #pragma unroll
    for (int j = 0; j < 8; ++j) {                       // prologue: tile 0
        r0[j] = xb4[(2 * n2) * 128 + f16 + j * 16];
        r1[j] = xb4[(2 * n2 + 1) * 128 + f16 + j * 16];
    }

    for (int t = 0; t < 4; ++t) {
        if (t) __syncthreads();                          // LDS reuse guard
        // ---- stage-writes from regs + x2 ----
        {
            float p0 = 0.f, p1 = 0.f;
            const int na = 2 * n2, nb = na + 1;
            #pragma unroll
            for (int j = 0; j < 8; ++j) {
                const float4 va = r0[j], vb = r1[j];
                p0 = fmaf(va.x, va.x, fmaf(va.y, va.y, fmaf(va.z, va.z, fmaf(va.w, va.w, p0))));
                p1 = fmaf(vb.x, vb.x, fmaf(vb.y, vb.y, fmaf(vb.z, vb.z, fmaf(vb.w, vb.w, p1))));
                const int f4n = f16 + j * 16;
                const int lowbit = (f4n & 1) << 2;
                const int chA = (((f4n >> 1) ^ (na & 7)) << 3) | lowbit;
                const int chB = (((f4n >> 1) ^ (nb & 7)) << 3) | lowbit;
                *reinterpret_cast<uint2*>(&fb16[na * 512 + chA]) =
                    make_uint2(pack2bf(va.x, va.y), pack2bf(va.z, va.w));
                *reinterpret_cast<uint2*>(&fb16[nb * 512 + chB]) =
                    make_uint2(pack2bf(vb.x, vb.y), pack2bf(vb.z, vb.w));
                const int fbase = f4n * 4;
                unsigned int* xw = reinterpret_cast<unsigned int*>(&xTl[0]);
                // xT[f][n]: u32 packs rows (2n2, 2n2+1); index in u32 units: (f*36 + 2*n2)/2
                xw[(fbase + 0) * 18 + n2] = pack2bf(va.x, vb.x);
                xw[(fbase + 1) * 18 + n2] = pack2bf(va.y, vb.y);
                xw[(fbase + 2) * 18 + n2] = pack2bf(va.z, vb.z);
                xw[(fbase + 3) * 18 + n2] = pack2bf(va.w, vb.w);
            }
            p0 += __shfl_xor(p0, 1); p0 += __shfl_xor(p0, 2);
            p0 += __shfl_xor(p0, 4); p0 += __shfl_xor(p0, 8);
            p1 += __shfl_xor(p1, 1); p1 += __shfl_xor(p1, 2);
            p1 += __shfl_xor(p1, 4); p1 += __shfl_xor(p1, 8);
            if (f16 == 0) { x2s[na] = p0; x2s[nb] = p1; }
        }
        // ---- prefetch next tile into regs (flies during phase 1+2) ----
        if (t < 3) {
            #pragma unroll
            for (int j = 0; j < 8; ++j) {
                r0[j] = xb4[((t + 1) * 32 + 2 * n2) * 128 + f16 + j * 16];
                r1[j] = xb4[((t + 1) * 32 + 2 * n2 + 1) * 128 + f16 + j * 16];
            }
        }
        __syncthreads();
        // ---- phase 1: MFMA xc^T + softmax (waves 0,1) ----
        if (wave < 2) {
            const int nl = wave * 16 + col;
            f32x4 c0 = {0.f, 0.f, 0.f, 0.f}, c1 = {0.f, 0.f, 0.f, 0.f};
            const unsigned short* arow0 = cwb + col * 512 + g * 8;
            const unsigned short* arow1 = arow0 + 16 * 512;
            const int nswz = (nl & 7) << 3;
            #pragma unroll
            for (int fs = 0; fs < 16; ++fs) {
                const short8 a0 = *(const short8*)(arow0 + fs * 32);
                const short8 a1 = *(const short8*)(arow1 + fs * 32);
                const short8 bf = *(const short8*)&fb16[nl * 512 + ((((fs * 4 + g) << 3)) ^ nswz)];
                c0 = __builtin_amdgcn_mfma_f32_16x16x32_bf16(a0, bf, c0, 0, 0, 0);
                c1 = __builtin_amdgcn_mfma_f32_16x16x32_bf16(a1, bf, c1, 0, 0, 0);
            }
            const float x2v = x2s[nl];
            float lg[8];
            #pragma unroll
            for (int r = 0; r < 4; ++r) {
                const int k0 = g * 4 + r;
                lg[r]     = fmaf(sm_s[k0],      fmaf(-2.f, c0[r], x2v), c2_s[k0]);
                lg[4 + r] = fmaf(sm_s[k0 + 16], fmaf(-2.f, c1[r], x2v), c2_s[k0 + 16]);
            }
            float m = lg[0];
            #pragma unroll
            for (int j = 1; j < 8; ++j) m = fmaxf(m, lg[j]);
            m = fmaxf(m, __shfl_xor(m, 16)); m = fmaxf(m, __shfl_xor(m, 32));
            float e[8], sum = 0.f;
            #pragma unroll
            for (int j = 0; j < 8; ++j) { e[j] = exp2f(lg[j] - m); sum += e[j]; }
            sum += __shfl_xor(sum, 16); sum += __shfl_xor(sum, 32);
            const float inv = 1.f / sum;
            #pragma unroll
            for (int r = 0; r < 4; ++r) {
                const float s0 = e[r] * inv, s1 = e[4 + r] * inv;
                sTl[(g * 4 + r) * 32 + nl]        = f2bf(s0);
                sTl[(16 + g * 4 + r) * 32 + nl]   = f2bf(s1);
                ssl[r] += s0; ssl[4 + r] += s1;
            }
        }
        __syncthreads();
        // ---- phase 2: MFMA enc[k][f] += sT[k][n] * x[n][f] (all 4 waves) ----
        {
            const int koff = (wave & 1) << 4;
            const int fh   = (wave >> 1) << 8;
            const short8 afrag = *(const short8*)&sTl[(koff + col) * 32 + g * 8];
            #pragma unroll
            for (int fb = 0; fb < 16; ++fb) {
                const unsigned short* bp = &xTl[(fh + fb * 16 + col) * 36 + g * 8];
                union { uint2 u[2]; short8 s; } bu;
                bu.u[0] = *reinterpret_cast<const uint2*>(bp);
                bu.u[1] = *reinterpret_cast<const uint2*>(bp + 4);
                accm[fb] = __builtin_amdgcn_mfma_f32_16x16x32_bf16(afrag, bu.s, accm[fb], 0, 0, 0);
            }
        }
    }
    // ---- s_sum writeback (waves 0,1; tiny atomic volume) ----
    if (wave < 2) {
        #pragma unroll
        for (int j = 0; j < 8; ++j) {
            float v = ssl[j];
            v += __shfl_xor(v, 1); v += __shfl_xor(v, 2);
            v += __shfl_xor(v, 4); v += __shfl_xor(v, 8);
            if ((lane & 15) == 0) {
                const int k = ((j & 4) << 2) + g * 4 + (j & 3);
                atomicAdd(&s_sum[b * Kk + k], v);
            }
        }
    }
    // ---- partial writeback: semantic [k][f] layout, 4x64B segments/store ----
    {
        const int koff = (wave & 1) << 4;
        const int fh   = (wave >> 1) << 8;
        float* basep = part + ((size_t)(b * 32 + cx) * Kk + koff + g * 4) * Ff + fh + col;
        #pragma unroll
        for (int fb = 0; fb < 16; ++fb)
            #pragma unroll
            for (int r = 0; r < 4; ++r)
                basep[r * Ff + fb * 16] = accm[fb][r];
    }
}

// ---------------------------------------------------------------------------
// enc_red: sum the 32 per-chunk partials -> enc[b][k][f]. grid 1024 x 256.
// ---------------------------------------------------------------------------
__global__ void enc_red(const float* __restrict__ scr, float* __restrict__ outp)
{
    const int idx = blockIdx.x * 256 + threadIdx.x;    // 0 .. 262143
    const int b   = idx >> 14;
    const int rem = idx & 16383;                       // k*512 + f
    const float* p = scr + (size_t)b * 32 * 16384 + rem;
    float a = 0.f;
    #pragma unroll
    for (int c = 0; c < 32; ++c) a += p[c * 16384];
    outp[idx] = a;
}

// ---------------------------------------------------------------------------
// enc_finish: enc = enc_red - s_sum*cw; BN + ReLU; sum over k; se_loss.
// ---------------------------------------------------------------------------
__global__ void enc_finish(const float* __restrict__ enc_acc,
                           const float* __restrict__ s_sum,
                           const float* __restrict__ cw,
                           const float* __restrict__ gamma,
                           const float* __restrict__ beta,
                           const float* __restrict__ mean,
                           const float* __restrict__ var,
                           const float* __restrict__ se_w,
                           const float* __restrict__ se_b,
                           float* __restrict__ enc_out,
                           float* __restrict__ se_out)
{
    __shared__ float ss[Kk];
    __shared__ float red[8];
    const int b = blockIdx.x, f = threadIdx.x;
    if (f < Kk) ss[f] = s_sum[b * Kk + f];
    __syncthreads();
    const float m  = mean[f];
    const float g  = gamma[f];
    const float bt = beta[f];
    const float iv = rsqrtf(var[f] + 1e-3f);
    float a = 0.f;
    #pragma unroll 4
    for (int k = 0; k < Kk; ++k) {
        float v = enc_acc[((long)b * Kk + k) * Ff + f] - ss[k] * cw[k * Ff + f];
        v = (v - m) * iv * g + bt;
        a += fmaxf(v, 0.f);
    }
    enc_out[b * Ff + f] = a;
    float p = a * se_w[f];
    p += __shfl_down(p, 32); p += __shfl_down(p, 16); p += __shfl_down(p, 8);
    p += __shfl_down(p, 4);  p += __shfl_down(p, 2);  p += __shfl_down(p, 1);
    if ((f & 63) == 0) red[f >> 6] = p;
    __syncthreads();
    if (f == 0) {
        float t = 0.f;
        #pragma unroll
        for (int i = 0; i < 8; ++i) t += red[i];
        se_out[b] = t + se_b[0];
    }
}

// ---------------------------------------------------------------------------
// attn_fc: grid 8 blocks x 512; W column-block read exactly once.
// ---------------------------------------------------------------------------
__global__ void attn_fc(const float* __restrict__ enc_out,
                        const float* __restrict__ W,
                        const float* __restrict__ bias,
                        float* __restrict__ attn)
{
    __shared__ float eo[Bb][Ff];                       // 32 KB
    const int t = threadIdx.x, fg = blockIdx.x;
    #pragma unroll
    for (int j = 0; j < 4; ++j)
        reinterpret_cast<float4*>(&eo[0][0])[t + j * 512] =
            reinterpret_cast<const float4*>(enc_out)[t + j * 512];
    __syncthreads();
    const int f  = fg * 64 + (t & 63);
    const int b0 = t >> 6;
    float a0 = bias[f], a1 = bias[f];
    #pragma unroll 8
    for (int fp = 0; fp < Ff; ++fp) {
        const float w = W[fp * Ff + f];
        a0 = fmaf(eo[b0][fp],     w, a0);
        a1 = fmaf(eo[b0 + 8][fp], w, a1);
    }
    attn[b0 * Ff + f]       = 1.f / (1.f + expf(-a0));
    attn[(b0 + 8) * Ff + f] = 1.f / (1.f + expf(-a1));
}

// ---------------------------------------------------------------------------
// bcast_mul: featuremaps = attn (broadcast over H,W) * inputs
// ---------------------------------------------------------------------------
__global__ void bcast_mul(const float4* __restrict__ x4,
                          const float* __restrict__ attn,
                          float4* __restrict__ o4)
{
    const int stride = gridDim.x * blockDim.x;
    const int total4 = Bb * HWn * Ff / 4;   // 8388608
    for (int i = blockIdx.x * blockDim.x + threadIdx.x; i < total4; i += stride) {
        const float4 v = x4[i];
        const int f4 = i & 127;
        const int bb = i >> 19;
        const float4 a = *reinterpret_cast<const float4*>(&attn[bb * Ff + f4 * 4]);
        o4[i] = make_float4(v.x * a.x, v.y * a.y, v.z * a.z, v.w * a.w);
    }
}

extern "C" void kernel_launch(void* const* d_in, const int* in_sizes, int n_in,
                              void* d_out, int out_size, void* d_ws, size_t ws_size,
                              hipStream_t stream)
{
    (void)in_sizes; (void)n_in; (void)out_size; (void)ws_size;
    const float* x     = (const float*)d_in[0];
    const float* cw    = (const float*)d_in[1];
    const float* smth  = (const float*)d_in[2];
    const float* gamma = (const float*)d_in[3];
    const float* beta  = (const float*)d_in[4];
    const float* mean  = (const float*)d_in[5];
    const float* var   = (const float*)d_in[6];
    const float* Wenc  = (const float*)d_in[7];
    const float* benc  = (const float*)d_in[8];
    const float* Wse   = (const float*)d_in[9];
    const float* bse   = (const float*)d_in[10];

    float* out = (float*)d_out;
    float* ws  = (float*)d_ws;
    float* ssum = ws + WS_SSUM;
    float* eout = ws + WS_EOUT;
    float* attn = ws + WS_ATTN;
    unsigned short* cwb = (unsigned short*)(ws + WS_CWB);
    float* c2l2 = ws + WS_C2;
    float* sml2 = ws + WS_SM;

    float* scr_part = out + SCR_PART;    // d_out featuremap region as scratch
    float* scr_red  = out + SCR_RED;

    hipMemsetAsync(ssum, 0, (size_t)Bb * Kk * sizeof(float), stream);
    prep<<<1, 256, 0, stream>>>(cw, smth, cwb, c2l2, sml2);
    enc_pass<<<dim3(32, Bb), 256, 0, stream>>>(x, cwb, c2l2, sml2, scr_part, ssum);
    enc_red<<<1024, 256, 0, stream>>>(scr_part, scr_red);
    enc_finish<<<Bb, 512, 0, stream>>>(scr_red, ssum, cw, gamma, beta, mean, var,
                                       Wse, bse, eout, out + (long)Bb * HWn * Ff);
    attn_fc<<<8, 512, 0, stream>>>(eout, Wenc, benc, attn);
    bcast_mul<<<2048, 256, 0, stream>>>((const float4*)x, attn, (float4*)out);
}